// Round 4
// baseline (274.470 us; speedup 1.0000x reference)
//
#include <hip/hip_runtime.h>
#include <hip/hip_bf16.h>
#include <stdint.h>

// SNN readout, fully fused: one kernel does W->bf16 conversion (LDS), the
// h = A @ W^T GEMM (MFMA, A staged via global_load_lds ring), and the time
// scan — h never touches HBM. Block = (b, og): 64 o's, all T=1000 steps.
// HBM traffic drops 262MB -> ~197MB; H workspace round-trip, wconv dispatch
// and scan dispatch eliminated; d_ws unused.
//   flt_t = ALPHA*flt_{t-1} + h_t ;  out_t = BETA*out_{t-1} + flt_{t-1}

#define ALPHA 0.95f
#define BETA  0.9f

constexpr int Bdim = 64, T = 1000, Idim = 512, Odim = 256;
constexpr int TC = 128;            // t-rows per chunk
constexpr int NC = 8;              // chunks per b (7 full + 104-row tail)
constexpr int KS = Idim / 32;      // 16 k-steps per chunk
constexpr int KK = NC * KS;        // 128 global k-steps
constexpr int HP = 66;             // Hs pitch (bank spread for quad writes)

typedef short bf16x8 __attribute__((ext_vector_type(8)));
typedef float f32x4  __attribute__((ext_vector_type(4)));

constexpr double dpow(double x, int n) { double r = 1; for (int i = 0; i < n; ++i) r *= x; return r; }

__device__ inline uint16_t f2bf(float a) {
  union { float f; uint32_t u; } x; x.f = a;
  return (uint16_t)((x.u + 0x7FFFu + ((x.u >> 16) & 1u)) >> 16);
}
__device__ inline float bf2f(uint16_t h) {
  union { uint32_t u; float f; } x; x.u = ((uint32_t)h) << 16; return x.f;
}

// async 16B global->LDS (wave-uniform LDS base; HW adds lane*16)
#define GLD16(g, l) __builtin_amdgcn_global_load_lds(                         \
    (const __attribute__((address_space(1))) uint32_t*)(g),                   \
    (__attribute__((address_space(3))) uint32_t*)(l), 16, 0, 0)

__device__ inline bf16x8 cvt8(float4 x0, float4 x1) {   // 8 fp32 -> bf16x8 RNE
  union { __hip_bfloat162 h[4]; bf16x8 v; } r;
  r.h[0] = __float22bfloat162_rn(make_float2(x0.x, x0.y));
  r.h[1] = __float22bfloat162_rn(make_float2(x0.z, x0.w));
  r.h[2] = __float22bfloat162_rn(make_float2(x1.x, x1.y));
  r.h[3] = __float22bfloat162_rn(make_float2(x1.z, x1.w));
  return r.v;
}

#define LGKM0 asm volatile("s_waitcnt lgkmcnt(0)" ::: "memory")
#define VMW4  asm volatile("s_waitcnt vmcnt(4)" ::: "memory")
#define SBAR  __builtin_amdgcn_s_barrier()

// grid 256 = (og 4) x (b_hi 8) x (b_lo 8); p%8 = b_lo keeps the 4 og-blocks
// of one b on one XCD -> A re-reads (x4) hit that XCD's L2, not HBM/L3.
__global__ __launch_bounds__(512) void fused(const float* __restrict__ A,
                                             const float* __restrict__ W,
                                             float* __restrict__ Out) {
  __shared__ uint16_t Ws[64 * 512];    // 64 KB bf16 W-slice, 16B-slot XOR swz
  __shared__ float    As[4][TC * 32];  // 64 KB fp32 A ring (swz via global addr)
  __shared__ uint16_t Hs[TC * HP];     // 16.5 KB h chunk (bf16)
  __shared__ float2   St[8][64];       // subchunk scan states
  __shared__ float2   Carry[64];       // (flt,out) carry across chunks

  const int tid  = threadIdx.x;
  const int lane = tid & 63;
  const int w    = tid >> 6;          // wave 0..7
  const int l15  = lane & 15;
  const int quad = lane >> 4;
  const int mq   = w & 3;             // m-quadrant: rows mq*32..+32
  const int nh   = w >> 2;            // n-half:    cols nh*32..+32

  const int p  = blockIdx.x;
  const int b  = ((p >> 3) & 7) * 8 + (p & 7);
  const int og = p >> 6;              // 0..3

  // ---- A staging geometry ----
  // stage tile = TC x 32 fp32 (16KB) = 2 GLD16/thread; rows r0, r0+8;
  // LDS slot lane&7 holds global 16B chunk g = (lane&7)^(row&7) (XOR folded
  // into the GLOBAL address; LDS stays linear as GLD16 requires).
  const int r0 = w * 16 + (lane >> 3);
  const int g  = (lane & 7) ^ (r0 & 7);
  const float* Ab0 = A + (size_t)b * T * Idim + g * 4;

#define STAGE(kk_) do {                                                        \
    const int kc_ = (kk_); const int cc_ = kc_ >> 4, ii_ = kc_ & 15;           \
    int ra_ = cc_ * TC + r0;     if (ra_ > T - 1) ra_ = T - 1;                 \
    int rb_ = cc_ * TC + r0 + 8; if (rb_ > T - 1) rb_ = T - 1;                 \
    char* d_ = (char*)As[kc_ & 3] + w * 2048;                                  \
    GLD16(Ab0 + (size_t)ra_ * Idim + ii_ * 32, d_);                            \
    GLD16(Ab0 + (size_t)rb_ * Idim + ii_ * 32, d_ + 1024);                     \
  } while (0)

  // prime the ring: depth-3 prefetch (6 loads in flight; vmcnt(4) per step)
  STAGE(0); STAGE(1); STAGE(2);

  // ---- prologue: convert W-slice fp32 -> bf16 into swizzled Ws ----
  {
    const int n  = tid >> 3;          // 0..63 (o within slice)
    const int s8 = tid & 7;
    const float* wp = W + (size_t)(og * 64 + n) * Idim;
#pragma unroll
    for (int rr = 0; rr < 8; ++rr) {
      int s = s8 + rr * 8;            // 16B slot 0..63 (k = s*8..s*8+8)
      float4 x0 = *(const float4*)(wp + s * 8);
      float4 x1 = *(const float4*)(wp + s * 8 + 4);
      *(bf16x8*)((char*)Ws + n * 1024 + ((s ^ (n & 7)) * 16)) = cvt8(x0, x1);
    }
  }
  if (tid < 64) Carry[tid] = make_float2(0.f, 0.f);
  LGKM0; SBAR;                        // Ws + Carry visible (vmcnt untouched)

  constexpr float AL = (float)dpow(0.95, 16);
  constexpr float BL = (float)dpow(0.90, 16);
  constexpr float WL = (float)((dpow(0.95, 16) - dpow(0.90, 16)) / (0.95 - 0.90));

  for (int c = 0; c < NC; ++c) {
    f32x4 acc[2][2] = {};
    // ---- GEMM k-loop: 16 steps, counted-vmcnt ring, 1 barrier/step ----
    for (int i = 0; i < KS; ++i) {
      const int kk = c * KS + i;
      VMW4;                           // own stage(kk) loads complete
      SBAR;                           // all waves' stage(kk) complete
      const float* Abuf = As[kk & 3];
      bf16x8 af[2], bfr[2];
#pragma unroll
      for (int mt = 0; mt < 2; ++mt) {
        const int m  = mq * 32 + mt * 16 + l15;
        const int s0 = (2 * quad) ^ (m & 7);       // slot of chunk 2q; ^1 -> 2q+1
        float4 x0 = *(const float4*)&Abuf[m * 32 + s0 * 4];
        float4 x1 = *(const float4*)&Abuf[m * 32 + (s0 ^ 1) * 4];
        af[mt] = cvt8(x0, x1);
      }
#pragma unroll
      for (int nt = 0; nt < 2; ++nt) {
        const int n  = nh * 32 + nt * 16 + l15;
        const int sl = (i * 4 + quad) ^ (n & 7);   // swizzled 16B slot
        bfr[nt] = *(const bf16x8*)((const char*)Ws + n * 1024 + sl * 16);
      }
#pragma unroll
      for (int mt = 0; mt < 2; ++mt)
#pragma unroll
        for (int nt = 0; nt < 2; ++nt)
          acc[mt][nt] = __builtin_amdgcn_mfma_f32_16x16x32_bf16(af[mt], bfr[nt], acc[mt][nt], 0, 0, 0);
      int nk = kk + 3; if (nk > KK - 1) nk = KK - 1;   // tail: benign dup of 127
      STAGE(nk);                      // overwrites buf[(kk-1)&3]: safe (see LGKM0)
      LGKM0;                          // drain own ds_reads BEFORE next barrier
    }

    // ---- epilogue: acc -> Hs (bf16). D layout: col=l15, row=quad*4+r ----
#pragma unroll
    for (int mt = 0; mt < 2; ++mt)
#pragma unroll
      for (int nt = 0; nt < 2; ++nt)
#pragma unroll
        for (int r = 0; r < 4; ++r) {
          const int tl = mq * 32 + mt * 16 + quad * 4 + r;
          const int o  = nh * 32 + nt * 16 + l15;
          Hs[tl * HP + o] = f2bf(acc[mt][nt][r]);
        }
    LGKM0; SBAR;

    // ---- scan phase 1: thread (sc=w, o=lane) local-scans 16 steps ----
    {
      const int sc = w, o = lane;
      float f = 0.f, u = 0.f;
#pragma unroll
      for (int j = 0; j < 16; ++j) {
        float h = bf2f(Hs[(sc * 16 + j) * HP + o]);
        float nu = BETA * u + f; f = ALPHA * f + h; u = nu;
      }
      St[sc][o] = make_float2(f, u);
    }
    LGKM0; SBAR;

    // ---- phase 2: combine 8 subchunks with persistent carry (wave 0) ----
    if (tid < 64) {
      float2 cv = Carry[tid];
      float f = cv.x, u = cv.y;
#pragma unroll
      for (int cc2 = 0; cc2 < 8; ++cc2) {
        float2 s = St[cc2][tid];
        St[cc2][tid] = make_float2(f, u);          // becomes subchunk init
        float nu = BL * u + WL * f + s.y;          // M^16 carry composition
        f = AL * f + s.x;
        u = nu;
      }
      Carry[tid] = make_float2(f, u);
    }
    LGKM0; SBAR;

    // ---- phase 3: rescan with inits, write Out (coalesced 4B/lane) ----
    {
      const int sc = w, o = lane;
      float2 s = St[sc][o];
      float f = s.x, u = s.y;
      const int tb = c * TC + sc * 16;
      float* op = Out + ((size_t)b * T + tb) * Odim + og * 64 + o;
#pragma unroll
      for (int j = 0; j < 16; ++j) {
        float h = bf2f(Hs[(sc * 16 + j) * HP + o]);
        float ov = BETA * u + f; f = ALPHA * f + h; u = ov;
        if (tb + j < T) op[j * Odim] = ov;
      }
    }
    // next chunk's VMW4+SBAR separates phase-3 reads from the next epilogue
  }
#undef STAGE
}

extern "C" void kernel_launch(void* const* d_in, const int* in_sizes, int n_in,
                              void* d_out, int out_size, void* d_ws, size_t ws_size,
                              hipStream_t stream) {
  (void)in_sizes; (void)n_in; (void)d_ws; (void)ws_size; (void)out_size;
  const float* A = (const float*)d_in[0];   // (B, T, I) fp32
  const float* W = (const float*)d_in[1];   // (O, I) fp32
  float* Out = (float*)d_out;               // (B, T, O) fp32
  fused<<<Bdim * 4, 512, 0, stream>>>(A, W, Out);
}